// Round 3
// baseline (123.685 us; speedup 1.0000x reference)
//
#include <hip/hip_runtime.h>
#include <math.h>

// LorentzConv1d bf16-MFMA im2col GEMM, round 3: latency-bound fix.
// MTILE 64 (2048 blocks -> ~8 blocks/CU), single __syncthreads, per-lane
// t_resc from LDS time column (broadcast reads), wave-independent MFMA phase.

#define BSZ   16
#define LLEN  8192
#define CIN   64
#define COUT  64
#define KW    5
#define LINF  316
#define MTILE 64
#define ROWS  (MTILE + 4)   // 68: halo PAD=2 each side
#define ASTR  72            // LDS row stride in bf16 (64+8), 144 B, 16B-aligned
#define KB    320           // 5 taps * 64 channels

typedef __attribute__((ext_vector_type(8))) short  short8;   // 8 bf16
typedef __attribute__((ext_vector_type(4))) float  float4v;  // MFMA acc

__device__ inline unsigned short f2bf(float f) {
    unsigned u = __builtin_bit_cast(unsigned int, f);
    u += 0x7FFFu + ((u >> 16) & 1u);
    return (unsigned short)(u >> 16);
}

__global__ __launch_bounds__(256) void prep_W(const float* __restrict__ W,
                                              unsigned short* __restrict__ Wb) {
    int i = blockIdx.x * 256 + threadIdx.x;
    if (i >= COUT * KB) return;
    int n   = i / KB;
    int kk  = i - n * KB;
    int tap = kk >> 6;
    int c   = kk & 63;
    float v = (c == 0) ? 0.f : W[n * LINF + 1 + (c - 1) * KW + tap];
    Wb[i] = f2bf(v);
}

__global__ __launch_bounds__(256) void lorentz_mfma(
    const float* __restrict__ x, const unsigned short* __restrict__ Wb,
    const float* __restrict__ W, const float* __restrict__ bias,
    float* __restrict__ out)
{
    __shared__ unsigned short At[ROWS * ASTR];
    __shared__ float tcol[ROWS];

    int tid = threadIdx.x;
    int blk = blockIdx.x;
    int b   = blk >> 7;                    // 128 blocks per batch row (8192/64)
    int l0  = (blk & 127) * MTILE;
    const float* xb = x + ((size_t)b * LLEN) * CIN;

    // ---- stage A tile: rows l0-2 .. l0+65, fp32 -> bf16 into LDS ----
    #pragma unroll
    for (int it = 0; it < 5; ++it) {
        int i = tid + it * 256;
        if (i < ROWS * 16) {
            int r = i >> 4, ch = i & 15;
            int row = l0 - 2 + r;
            bool inr = (row >= 0) && (row < LLEN);
            int rowc = min(max(row, 0), LLEN - 1);
            float4 v = ((const float4*)(xb + (size_t)rowc * CIN))[ch];
            if (!inr) { v.x = (ch == 0) ? 1.f : 0.f; v.y = 0.f; v.z = 0.f; v.w = 0.f; }
            if (ch == 0) tcol[r] = v.x;
            ushort4 pk;
            pk.x = f2bf(v.x); pk.y = f2bf(v.y); pk.z = f2bf(v.z); pk.w = f2bf(v.w);
            *(ushort4*)&At[r * ASTR + ch * 4] = pk;
        }
    }
    __syncthreads();

    int lane = tid & 63, wv = tid >> 6;
    int col = lane & 15, quad = lane >> 4;
    int m0 = wv * 16;                      // wave's 16-row M-subtile

    // ---- per-lane t_resc for its 4 output rows (quad*4+reg) ----
    // window of 8 time values starting at m0+quad*4 (16B-aligned)
    float tw[8];
    {
        const float4* tp = (const float4*)&tcol[m0 + quad * 4];
        float4 a = tp[0], c = tp[1];
        tw[0] = a.x; tw[1] = a.y; tw[2] = a.z; tw[3] = a.w;
        tw[4] = c.x; tw[5] = c.y; tw[6] = c.z; tw[7] = c.w;
    }
    float trsc[4];
    #pragma unroll
    for (int reg = 0; reg < 4; ++reg) {
        float s = 0.f;
        #pragma unroll
        for (int t = 0; t < KW; ++t) { float v = tw[reg + t]; s += v * v; }
        trsc[reg] = sqrtf(s - (float)(KW - 1));
    }

    float4v acc[4];
    #pragma unroll
    for (int nt = 0; nt < 4; ++nt) acc[nt] = (float4v){0.f, 0.f, 0.f, 0.f};

    // ---- GEMM: 5 taps x 2 ksteps of 32, 4 N-subtiles ----
    #pragma unroll
    for (int tap = 0; tap < KW; ++tap) {
        #pragma unroll
        for (int ks = 0; ks < 2; ++ks) {
            // A fragment: m = col, k = quad*8+j ; LDS row = pos + tap
            short8 afr = *(const short8*)&At[(m0 + col + tap) * ASTR + ks * 32 + quad * 8];
            #pragma unroll
            for (int nt = 0; nt < 4; ++nt) {
                short8 bfr = *(const short8*)(Wb + (nt * 16 + col) * KB
                                              + tap * 64 + ks * 32 + quad * 8);
                acc[nt] = __builtin_amdgcn_mfma_f32_16x16x32_bf16(afr, bfr, acc[nt], 0, 0, 0);
            }
        }
    }

    // ---- epilogue: + bias + t_resc*W_time, output Lorentz, store ----
    float bo[4], w0[4];
    #pragma unroll
    for (int nt = 0; nt < 4; ++nt) {
        int o = nt * 16 + col;
        bo[nt] = bias[o];
        w0[nt] = W[o * LINF];
    }
    float y[4][4];                         // [nt][reg]
    float ssq[4] = {0.f, 0.f, 0.f, 0.f};
    #pragma unroll
    for (int reg = 0; reg < 4; ++reg) {
        #pragma unroll
        for (int nt = 0; nt < 4; ++nt) {
            float v = acc[nt][reg] + bo[nt] + trsc[reg] * w0[nt];
            y[nt][reg] = v;
            bool isc0 = (nt == 0) && (col == 0);
            ssq[reg] += isc0 ? 0.f : v * v;
        }
    }
    #pragma unroll
    for (int reg = 0; reg < 4; ++reg) {
        #pragma unroll
        for (int msk = 1; msk < 16; msk <<= 1)
            ssq[reg] += __shfl_xor(ssq[reg], msk, 64);
        if (col == 0) y[0][reg] = sqrtf(ssq[reg] + 1.f);
    }
    size_t obase = (size_t)blk * MTILE + m0;
    #pragma unroll
    for (int reg = 0; reg < 4; ++reg) {
        float* orow = out + (obase + quad * 4 + reg) * COUT;
        #pragma unroll
        for (int nt = 0; nt < 4; ++nt)
            orow[nt * 16 + col] = y[nt][reg];
    }
}

extern "C" void kernel_launch(void* const* d_in, const int* in_sizes, int n_in,
                              void* d_out, int out_size, void* d_ws, size_t ws_size,
                              hipStream_t stream) {
    const float* x    = (const float*)d_in[0];
    const float* W    = (const float*)d_in[1];
    const float* bias = (const float*)d_in[2];
    float* out = (float*)d_out;
    unsigned short* Wb = (unsigned short*)d_ws;   // 64*320*2 = 40960 B scratch

    hipLaunchKernelGGL(prep_W, dim3((COUT * KB + 255) / 256), dim3(256), 0, stream,
                       W, Wb);
    hipLaunchKernelGGL(lorentz_mfma, dim3(BSZ * LLEN / MTILE), dim3(256), 0, stream,
                       x, Wb, W, bias, out);
}

// Round 4
// 100.282 us; speedup vs baseline: 1.2334x; 1.2334x over previous
//
#include <hip/hip_runtime.h>
#include <math.h>

// LorentzConv1d bf16-MFMA, round 4: kill K-loop global loads + pipeline.
// B panel (K=320 x 32 N-cols per wave) preloaded to registers (80 VGPR);
// K-loop is pure ds_read_b128 + MFMA. Persistent blocks (2 tiles each) with
// double-buffered LDS A-staging: tile i+1 global loads in flight across
// tile i's MFMA work. One barrier per tile; epilogue ssq exchanged via LDS.

#define BSZ   16
#define LLEN  8192
#define CIN   64
#define COUT  64
#define KW    5
#define LINF  316
#define MTILE 64
#define ROWS  68            // MTILE + 2*PAD
#define ASTR  72            // LDS row stride (bf16): 144 B, 16B-aligned
#define KB    320           // 5 taps * 64 channels
#define TPB   2             // tiles per block
#define NTILES (BSZ * LLEN / MTILE)   // 2048
#define GRID   (NTILES / TPB)         // 1024

typedef __attribute__((ext_vector_type(8))) short  short8;
typedef __attribute__((ext_vector_type(4))) float  float4v;

__device__ inline unsigned short f2bf(float f) {
    unsigned u = __builtin_bit_cast(unsigned int, f);
    u += 0x7FFFu + ((u >> 16) & 1u);
    return (unsigned short)(u >> 16);
}

__global__ __launch_bounds__(256) void prep_W(const float* __restrict__ W,
                                              unsigned short* __restrict__ Wb) {
    int i = blockIdx.x * 256 + threadIdx.x;
    if (i >= COUT * KB) return;
    int n   = i / KB;
    int kk  = i - n * KB;
    int tap = kk >> 6;
    int c   = kk & 63;
    float v = (c == 0) ? 0.f : W[n * LINF + 1 + (c - 1) * KW + tap];
    Wb[i] = f2bf(v);
}

__global__ __launch_bounds__(256, 3) void lorentz_mfma(
    const float* __restrict__ x, const unsigned short* __restrict__ Wb,
    const float* __restrict__ W, const float* __restrict__ bias,
    float* __restrict__ out)
{
    __shared__ unsigned short At[2][ROWS * ASTR];
    __shared__ float tcol[2][72];          // 72: keeps each buffer 16B-aligned
    __shared__ float pss[2][2][64];        // [buf][nhalf][row]

    int tid  = threadIdx.x;
    int lane = tid & 63;
    int wv   = tid >> 6;
    int col  = lane & 15, quad = lane >> 4;
    int nhalf = wv & 1;                    // which 32 of 64 output cols
    int mbase = (wv >> 1) * 32;            // which 32 of 64 rows

    int tile0 = blockIdx.x * TPB;

    // ---- preload B panel for this wave's 32 N-cols: 20 frags = 80 VGPR ----
    short8 breg[2][10];
    #pragma unroll
    for (int j = 0; j < 2; ++j) {
        const unsigned short* bp = Wb + (nhalf * 32 + j * 16 + col) * KB + quad * 8;
        #pragma unroll
        for (int kk = 0; kk < 10; ++kk)
            breg[j][kk] = *(const short8*)(bp + kk * 32);
    }
    float bo[2], w0[2];
    #pragma unroll
    for (int j = 0; j < 2; ++j) {
        int n = nhalf * 32 + j * 16 + col;
        bo[j] = bias[n];
        w0[j] = W[n * LINF];               // time-feature weight
    }

    float4 sreg[5];
    bool   sin[5];

    auto stage_load = [&](int tile) {
        int b  = tile >> 7;                // 128 tiles per batch row
        int l0 = (tile & 127) * MTILE;
        const float* xb = x + ((size_t)b * LLEN) * CIN;
        #pragma unroll
        for (int itc = 0; itc < 5; ++itc) {
            int i = tid + itc * 256;
            if (i < ROWS * 16) {
                int r = i >> 4, ch = i & 15;
                int row = l0 - 2 + r;
                sin[itc] = (row >= 0) && (row < LLEN);
                int rowc = min(max(row, 0), LLEN - 1);
                sreg[itc] = ((const float4*)(xb + (size_t)rowc * CIN))[ch];
            }
        }
    };
    auto stage_write = [&](int nb) {
        #pragma unroll
        for (int itc = 0; itc < 5; ++itc) {
            int i = tid + itc * 256;
            if (i < ROWS * 16) {
                int r = i >> 4, ch = i & 15;
                float4 v = sreg[itc];
                if (!sin[itc]) { v.x = (ch == 0) ? 1.f : 0.f; v.y = 0.f; v.z = 0.f; v.w = 0.f; }
                if (ch == 0) tcol[nb][r] = v.x;
                ushort4 pk;
                pk.x = f2bf(v.x); pk.y = f2bf(v.y); pk.z = f2bf(v.z); pk.w = f2bf(v.w);
                *(ushort4*)&At[nb][r * ASTR + ch * 4] = pk;
            }
        }
    };

    // ---- prologue: stage tile 0 into buffer 0 ----
    stage_load(tile0);
    stage_write(0);
    __syncthreads();

    int cur = 0;
    #pragma unroll
    for (int it = 0; it < TPB; ++it) {
        int tile = tile0 + it;
        bool more = (it + 1 < TPB);
        if (more) stage_load(tile + 1);    // global loads in flight over MFMA

        // ---- K-loop: pure LDS + MFMA ----
        float4v acc[2][2];                 // [msub][j]
        #pragma unroll
        for (int ms = 0; ms < 2; ++ms)
            #pragma unroll
            for (int j = 0; j < 2; ++j)
                acc[ms][j] = (float4v){0.f, 0.f, 0.f, 0.f};
        #pragma unroll
        for (int kk = 0; kk < 10; ++kk) {
            int tap = kk >> 1, ks = kk & 1;
            #pragma unroll
            for (int ms = 0; ms < 2; ++ms) {
                short8 afr = *(const short8*)&At[cur][(mbase + ms * 16 + col + tap) * ASTR
                                                     + ks * 32 + quad * 8];
                acc[ms][0] = __builtin_amdgcn_mfma_f32_16x16x32_bf16(afr, breg[0][kk], acc[ms][0], 0, 0, 0);
                acc[ms][1] = __builtin_amdgcn_mfma_f32_16x16x32_bf16(afr, breg[1][kk], acc[ms][1], 0, 0, 0);
            }
        }

        // ---- t_resc per (msub, reg) from fp32 time column ----
        float trs[2][4];
        #pragma unroll
        for (int ms = 0; ms < 2; ++ms) {
            int p0 = mbase + ms * 16 + quad * 4;
            float4 a = *(const float4*)&tcol[cur][p0];
            float4 c = *(const float4*)&tcol[cur][p0 + 4];
            float tw[8] = {a.x, a.y, a.z, a.w, c.x, c.y, c.z, c.w};
            #pragma unroll
            for (int reg = 0; reg < 4; ++reg) {
                float s = 0.f;
                #pragma unroll
                for (int t = 0; t < KW; ++t) { float v = tw[reg + t]; s += v * v; }
                trs[ms][reg] = sqrtf(s - (float)(KW - 1));
            }
        }

        // ---- partial epilogue: y, per-row ssq over this wave's 32 cols ----
        float y[2][2][4];                  // [ms][j][reg]
        float sq[2][4];
        #pragma unroll
        for (int ms = 0; ms < 2; ++ms)
            #pragma unroll
            for (int reg = 0; reg < 4; ++reg) {
                float s = 0.f;
                #pragma unroll
                for (int j = 0; j < 2; ++j) {
                    float v = acc[ms][j][reg] + bo[j] + trs[ms][reg] * w0[j];
                    y[ms][j][reg] = v;
                    bool isc0 = (nhalf == 0) && (j == 0) && (col == 0);
                    s += isc0 ? 0.f : v * v;
                }
                sq[ms][reg] = s;
            }
        #pragma unroll
        for (int ms = 0; ms < 2; ++ms)
            #pragma unroll
            for (int reg = 0; reg < 4; ++reg) {
                #pragma unroll
                for (int msk = 1; msk < 16; msk <<= 1)
                    sq[ms][reg] += __shfl_xor(sq[ms][reg], msk, 64);
                if (col == 0)
                    pss[cur][nhalf][mbase + ms * 16 + quad * 4 + reg] = sq[ms][reg];
            }

        if (more) stage_write(cur ^ 1);    // convert + fill other buffer
        __syncthreads();                   // publishes pss[cur] AND At[cur^1]

        // ---- finish: combine halves, Lorentz-replace o=0, store ----
        #pragma unroll
        for (int ms = 0; ms < 2; ++ms)
            #pragma unroll
            for (int reg = 0; reg < 4; ++reg) {
                int row = mbase + ms * 16 + quad * 4 + reg;
                float tot = sq[ms][reg] + pss[cur][1 ^ nhalf][row];
                if (nhalf == 0 && col == 0)
                    y[ms][0][reg] = sqrtf(tot + 1.f);
                float* orow = out + ((size_t)tile * MTILE + row) * COUT + nhalf * 32 + col;
                orow[0]  = y[ms][0][reg];
                orow[16] = y[ms][1][reg];
            }
        cur ^= 1;
    }
}

extern "C" void kernel_launch(void* const* d_in, const int* in_sizes, int n_in,
                              void* d_out, int out_size, void* d_ws, size_t ws_size,
                              hipStream_t stream) {
    const float* x    = (const float*)d_in[0];
    const float* W    = (const float*)d_in[1];
    const float* bias = (const float*)d_in[2];
    float* out = (float*)d_out;
    unsigned short* Wb = (unsigned short*)d_ws;   // 40960 B scratch

    hipLaunchKernelGGL(prep_W, dim3((COUT * KB + 255) / 256), dim3(256), 0, stream,
                       W, Wb);
    hipLaunchKernelGGL(lorentz_mfma, dim3(GRID), dim3(256), 0, stream,
                       x, Wb, W, bias, out);
}